// Round 12
// baseline (170.877 us; speedup 1.0000x reference)
//
#include <hip/hip_runtime.h>
#include <hip/hip_bf16.h>
#include <math.h>

// ---------------------------------------------------------------------------
// MaskAdaptiveLogSoftmax, round 12:
//   classify: bucket tokens by target cluster (1 block, deterministic values)
//   pack_a:   x rows -> bf16 fragments in MFMA-native order (coalesced)
//   gemm:     W-stationary 64-voc tiles, 256 thr / 4 waves, swapped operands
//             (D rows = vocab). NEW: epilogue transposes through a per-wave
//             LDS buffer so lws stores are 64B-contiguous per token row
//             (16 x 64B full-line segments per instr; no partial-line
//             write-allocate).
//   finalize: one block per token row. NEW: active row loaded ONCE into
//             registers (10 x u16x8, static idx), sumexp from regs, active
//             span written from regs; inactive spans = two -L range loops.
// ---------------------------------------------------------------------------

typedef __attribute__((ext_vector_type(4))) float f32x4;
typedef __attribute__((ext_vector_type(8))) short bf16x8;
typedef __attribute__((ext_vector_type(4))) unsigned short u16x4;
typedef __attribute__((ext_vector_type(8))) unsigned short u16x8;

__device__ __forceinline__ unsigned int f2bf(float f) {
    union { float f; unsigned int u; } cv; cv.f = f;
    unsigned int u = cv.u + 0x7fffu + ((cv.u >> 16) & 1u);  // RNE
    return u >> 16;
}
__device__ __forceinline__ float bf2f(unsigned short h) {
    union { unsigned int u; float f; } cv; cv.u = ((unsigned int)h) << 16;
    return cv.f;
}

__global__ __launch_bounds__(1024) void classify_kernel(
    const int* __restrict__ targets, int* cnt, int* lists,
    int n_tok, int c1, int c2) {
    __shared__ int lcnt[3];
    int tid = threadIdx.x;
    if (tid < 3) lcnt[tid] = 0;
    __syncthreads();
    for (int t = tid; t < n_tok; t += 1024) {
        int tgt = targets[t];
        int c = (tgt < c1) ? 0 : ((tgt < c2) ? 1 : 2);
        int pos = atomicAdd(&lcnt[c], 1);
        lists[c * n_tok + pos] = t;
    }
    __syncthreads();
    if (tid < 3) cnt[tid] = lcnt[tid];
}

// ---- pack x-fragments: group = 16 tokens; cell (k0, lane) = 16B ----
__global__ __launch_bounds__(512) void pack_a_kernel(
    const float* __restrict__ x, const int* __restrict__ lists,
    const int* __restrict__ cnt, unsigned short* __restrict__ packA,
    int n_tok) {
    int it0 = (cnt[0] + 255) >> 8, it1 = (cnt[1] + 255) >> 8,
        it2 = (cnt[2] + 255) >> 8;
    int g0 = it0 * 16, g1 = it1 * 16, g2 = it2 * 16;
    int gb = blockIdx.x;
    int c, g, n, base;
    if (gb < g0)                { c = 0; g = gb;            n = cnt[0]; base = 0; }
    else if (gb < g0 + g1)      { c = 1; g = gb - g0;       n = cnt[1]; base = g0; }
    else if (gb < g0 + g1 + g2) { c = 2; g = gb - g0 - g1;  n = cnt[2]; base = g0 + g1; }
    else return;

    int tid = threadIdx.x;
    int k0 = tid >> 6, lane = tid & 63;
    int l15 = lane & 15, lg = lane >> 4;
    int pos = g * 16 + l15;
    int tok = (pos < n) ? lists[c * n_tok + pos] : -1;
    uint4 pk = make_uint4(0u, 0u, 0u, 0u);
    if (tok >= 0) {
        const float* src = x + (size_t)tok * 256 + k0 * 32 + lg * 8;
        float4 lo = *(const float4*)src;
        float4 hi = *(const float4*)(src + 4);
        pk.x = f2bf(lo.x) | (f2bf(lo.y) << 16);
        pk.y = f2bf(lo.z) | (f2bf(lo.w) << 16);
        pk.z = f2bf(hi.x) | (f2bf(hi.y) << 16);
        pk.w = f2bf(hi.z) | (f2bf(hi.w) << 16);
    }
    *(uint4*)(packA + ((size_t)(base + g) * 8 + k0) * 512 + lane * 8) = pk;
}

// ---- W-stationary GEMM: 64-voc tiles, 256 threads = 4 waves ----
#define TROW 136   // LDS transpose row stride (bytes): 2-way write conflicts
__global__ __launch_bounds__(256, 3) void gemm_ws_kernel(
    const unsigned short* __restrict__ packA,
    const float* __restrict__ w0, const float* __restrict__ w1,
    const float* __restrict__ w2,
    const float* __restrict__ b0, const float* __restrict__ b1,
    const float* __restrict__ b2,
    const int* __restrict__ lists, const int* __restrict__ cnt,
    int V0, int V1, int V2, int nv0, int nv1,
    unsigned short* __restrict__ lws, int lstride, int n_tok) {

    __shared__ __align__(16) unsigned char wlds[64 * 512];      // 32 KB
    __shared__ int tok_lds[2048];                               // 8 KB
    __shared__ __align__(16) unsigned char tlds[4 * 16 * TROW]; // 8.5 KB

    int bid = blockIdx.x;
    int c, vt;
    if (bid < nv0)            { c = 0; vt = bid; }
    else if (bid < nv0 + nv1) { c = 1; vt = bid - nv0; }
    else                      { c = 2; vt = bid - nv0 - nv1; }

    const float* Wc; const float* Bc; int Vc;
    if (c == 0)      { Wc = w0; Bc = b0; Vc = V0; }
    else if (c == 1) { Wc = w1; Bc = b1; Vc = V1; }
    else             { Wc = w2; Bc = b2; Vc = V2; }

    int it0 = (cnt[0] + 255) >> 8, it1 = (cnt[1] + 255) >> 8;
    int baseg = (c == 0) ? 0 : ((c == 1) ? it0 * 16 : (it0 + it1) * 16);

    int n = cnt[c];
    int nIter = (n + 255) >> 8;
    int v0 = vt * 64;
    int tid = threadIdx.x;

    // ---- stage W tile (64 rows x 256 k) fp32 -> bf16 LDS in frag order ----
    #pragma unroll
    for (int u0 = 0; u0 < 2; ++u0) {
        int u = u0 * 256 + tid;
        int row = u >> 3, seg = u & 7;
        int v = v0 + row;
        float4 f[8];
        if (v < Vc) {
            const float* src = Wc + (size_t)v * 256 + seg * 32;
            #pragma unroll
            for (int j = 0; j < 8; ++j) f[j] = *(const float4*)(src + j * 4);
        } else {
            #pragma unroll
            for (int j = 0; j < 8; ++j) f[j] = make_float4(0.f, 0.f, 0.f, 0.f);
        }
        unsigned fb = (unsigned)(((row >> 4) * 8 + seg) * 1024);
        int l15r = row & 15;
        #pragma unroll
        for (int j = 0; j < 4; ++j) {
            uint4 pk;
            pk.x = f2bf(f[2*j].x)   | (f2bf(f[2*j].y)   << 16);
            pk.y = f2bf(f[2*j].z)   | (f2bf(f[2*j].w)   << 16);
            pk.z = f2bf(f[2*j+1].x) | (f2bf(f[2*j+1].y) << 16);
            pk.w = f2bf(f[2*j+1].z) | (f2bf(f[2*j+1].w) << 16);
            *(uint4*)(wlds + fb + (j * 16 + l15r) * 16) = pk;
        }
    }
    for (int i = tid; i < nIter * 256; i += 256)
        tok_lds[i] = (i < n) ? lists[c * n_tok + i] : -1;
    __syncthreads();
    // no block barriers after this point

    int lane = tid & 63;
    int wid  = tid >> 6;
    int lg = lane >> 4, l15 = lane & 15;
    const char* pA = (const char*)packA;
    unsigned char* tb = tlds + wid * (16 * TROW);   // per-wave private

    // bias per lane: vocab rows v0 + mv*16 + lg*4 + r; -inf for vocab pad
    float bvv[4][4];
    #pragma unroll
    for (int mv = 0; mv < 4; ++mv) {
        int vbase = v0 + mv * 16 + lg * 4;
        #pragma unroll
        for (int r = 0; r < 4; ++r)
            bvv[mv][r] = (vbase + r < Vc) ? Bc[vbase + r]
                                          : -__builtin_huge_valf();
    }
    int t16 = lane >> 2, prt = lane & 3;   // read-phase mapping

    for (int it = 0; it < nIter; ++it) {
        int tbase = it * 256 + wid * 64;
        if (tbase >= n) continue;   // wave-uniform, no barriers -> safe
        const char* ga = pA + (size_t)(baseg + it * 16 + wid * 4) * 8192 + lane * 16;

        f32x4 acc[4][4];   // [mv = vocab-16-group][nt = token-16-group]
        #pragma unroll
        for (int mv = 0; mv < 4; ++mv)
            #pragma unroll
            for (int nt = 0; nt < 4; ++nt)
                acc[mv][nt] = (f32x4){0.f, 0.f, 0.f, 0.f};

        #pragma unroll
        for (int k0 = 0; k0 < 8; ++k0) {
            bf16x8 w[4], xf[4];
            #pragma unroll
            for (int mv = 0; mv < 4; ++mv)
                w[mv] = *(const bf16x8*)(wlds + (mv * 8 + k0) * 1024 + lane * 16);
            #pragma unroll
            for (int nt = 0; nt < 4; ++nt)
                xf[nt] = *(const bf16x8*)(ga + nt * 8192 + k0 * 1024);
            #pragma unroll
            for (int mv = 0; mv < 4; ++mv)
                #pragma unroll
                for (int nt = 0; nt < 4; ++nt)
                    acc[mv][nt] = __builtin_amdgcn_mfma_f32_16x16x32_bf16(
                        w[mv], xf[nt], acc[mv][nt], 0, 0, 0);
        }

        // ---- epilogue: LDS transpose -> 64B-contiguous lws stores ----
        #pragma unroll
        for (int nt = 0; nt < 4; ++nt) {
            #pragma unroll
            for (int mv = 0; mv < 4; ++mv) {
                u16x4 pk;
                pk.x = (unsigned short)f2bf(acc[mv][nt][0] + bvv[mv][0]);
                pk.y = (unsigned short)f2bf(acc[mv][nt][1] + bvv[mv][1]);
                pk.z = (unsigned short)f2bf(acc[mv][nt][2] + bvv[mv][2]);
                pk.w = (unsigned short)f2bf(acc[mv][nt][3] + bvv[mv][3]);
                *(u16x4*)(tb + l15 * TROW + mv * 32 + lg * 8) = pk;
            }
            asm volatile("s_waitcnt lgkmcnt(0)" ::: "memory");
            __builtin_amdgcn_sched_barrier(0);
            // read token-major: lane = t16*4 + prt; units prt and prt+4
            const unsigned char* rb = tb + t16 * TROW + prt * 16;
            u16x4 a0 = *(const u16x4*)(rb + 0);
            u16x4 a1 = *(const u16x4*)(rb + 8);
            u16x4 b0v = *(const u16x4*)(rb + 64);
            u16x4 b1v = *(const u16x4*)(rb + 72);
            int tokid = tok_lds[tbase + nt * 16 + t16];
            if (tokid >= 0) {
                unsigned short* dst = lws + (size_t)tokid * lstride + v0 + prt * 8;
                u16x8 s0 = {a0.x, a0.y, a0.z, a0.w, a1.x, a1.y, a1.z, a1.w};
                u16x8 s1 = {b0v.x, b0v.y, b0v.z, b0v.w, b1v.x, b1v.y, b1v.z, b1v.w};
                *(u16x8*)dst = s0;
                *(u16x8*)(dst + 32) = s1;
            }
            asm volatile("s_waitcnt lgkmcnt(0)" ::: "memory");
            __builtin_amdgcn_sched_barrier(0);
        }
    }
}

// ---- fused sumexp + finalize: one block per token row, reg-cached ----
__global__ __launch_bounds__(256, 4) void finalize_kernel(
    float* __restrict__ out, const unsigned short* __restrict__ lws,
    int lstride, const int* __restrict__ targets, int c1, int c2, int N) {
    __shared__ float sred[4];
    __shared__ float sL;

    int t = blockIdx.x;
    int tid = threadIdx.x;
    int tgt = targets[t];
    int l, r, V;
    if (tgt < c1)      { l = 0;  r = c1; V = c1; }
    else if (tgt < c2) { l = c1; r = c2; V = c2 - c1; }
    else               { l = c2; r = N;  V = N - c2; }

    const unsigned short* lrow = lws + (size_t)t * lstride;
    int Vp8 = (V + 7) & ~7;            // pad logits are -inf -> exp()=0
    bool cached = (Vp8 <= 20480);      // 10 regs x 2048 span

    u16x8 rc[10];
    float s = 0.f;
    if (cached) {
        #pragma unroll
        for (int j = 0; j < 10; ++j) {
            int idx = tid * 8 + j * 2048;
            if (idx < Vp8) {
                u16x8 u = *(const u16x8*)(lrow + idx);
                rc[j] = u;
                s += __expf(bf2f(u.s0)) + __expf(bf2f(u.s1))
                   + __expf(bf2f(u.s2)) + __expf(bf2f(u.s3))
                   + __expf(bf2f(u.s4)) + __expf(bf2f(u.s5))
                   + __expf(bf2f(u.s6)) + __expf(bf2f(u.s7));
            }
        }
    } else {
        for (int i = tid * 8; i < Vp8; i += 2048) {
            u16x8 u = *(const u16x8*)(lrow + i);
            s += __expf(bf2f(u.s0)) + __expf(bf2f(u.s1))
               + __expf(bf2f(u.s2)) + __expf(bf2f(u.s3))
               + __expf(bf2f(u.s4)) + __expf(bf2f(u.s5))
               + __expf(bf2f(u.s6)) + __expf(bf2f(u.s7));
        }
    }
    s += __shfl_down(s, 32); s += __shfl_down(s, 16); s += __shfl_down(s, 8);
    s += __shfl_down(s, 4);  s += __shfl_down(s, 2);  s += __shfl_down(s, 1);
    if ((tid & 63) == 0) sred[tid >> 6] = s;
    __syncthreads();
    if (tid == 0)
        sL = logf(sred[0] + sred[1] + sred[2] + sred[3] + (float)(N - V));
    __syncthreads();
    float L = sL;

    float* orow = out + (size_t)t * N;
    // active span from registers (or re-read fallback)
    if (cached) {
        #pragma unroll
        for (int j = 0; j < 10; ++j) {
            int idx = tid * 8 + j * 2048;
            if (idx < Vp8) {
                u16x8 u = rc[j];
                if (idx + 8 <= V) {
                    f32x4 r0 = (f32x4){bf2f(u.s0) - L, bf2f(u.s1) - L,
                                       bf2f(u.s2) - L, bf2f(u.s3) - L};
                    f32x4 r1 = (f32x4){bf2f(u.s4) - L, bf2f(u.s5) - L,
                                       bf2f(u.s6) - L, bf2f(u.s7) - L};
                    __builtin_nontemporal_store(r0, (f32x4*)(orow + l + idx));
                    __builtin_nontemporal_store(r1, (f32x4*)(orow + l + idx + 4));
                } else {
                    float vals[8] = {bf2f(u.s0), bf2f(u.s1), bf2f(u.s2),
                                     bf2f(u.s3), bf2f(u.s4), bf2f(u.s5),
                                     bf2f(u.s6), bf2f(u.s7)};
                    #pragma unroll
                    for (int k = 0; k < 8; ++k)
                        if (idx + k < V) orow[l + idx + k] = vals[k] - L;
                }
            }
        }
    } else {
        for (int i = tid * 8; i < Vp8; i += 2048) {
            u16x8 u = *(const u16x8*)(lrow + i);
            if (i + 8 <= V) {
                f32x4 r0 = (f32x4){bf2f(u.s0) - L, bf2f(u.s1) - L,
                                   bf2f(u.s2) - L, bf2f(u.s3) - L};
                f32x4 r1 = (f32x4){bf2f(u.s4) - L, bf2f(u.s5) - L,
                                   bf2f(u.s6) - L, bf2f(u.s7) - L};
                __builtin_nontemporal_store(r0, (f32x4*)(orow + l + i));
                __builtin_nontemporal_store(r1, (f32x4*)(orow + l + i + 4));
            } else {
                float vals[8] = {bf2f(u.s0), bf2f(u.s1), bf2f(u.s2),
                                 bf2f(u.s3), bf2f(u.s4), bf2f(u.s5),
                                 bf2f(u.s6), bf2f(u.s7)};
                #pragma unroll
                for (int k = 0; k < 8; ++k)
                    if (i + k < V) orow[l + i + k] = vals[k] - L;
            }
        }
    }
    // inactive spans: [0, l) and [r, N)
    f32x4 neg = (f32x4){-L, -L, -L, -L};
    for (int i4 = tid * 4; i4 < l; i4 += 1024)
        __builtin_nontemporal_store(neg, (f32x4*)(orow + i4));
    for (int i4 = r + tid * 4; i4 < N; i4 += 1024)
        __builtin_nontemporal_store(neg, (f32x4*)(orow + i4));
}

extern "C" void kernel_launch(void* const* d_in, const int* in_sizes, int n_in,
                              void* d_out, int out_size, void* d_ws, size_t ws_size,
                              hipStream_t stream) {
    const float* x       = (const float*)d_in[0];
    const int*   targets = (const int*)d_in[1];
    const float* w0      = (const float*)d_in[2];
    const float* w1      = (const float*)d_in[3];
    const float* w2      = (const float*)d_in[4];
    const float* b0      = (const float*)d_in[5];
    const float* b1      = (const float*)d_in[6];
    const float* b2      = (const float*)d_in[7];
    float* out = (float*)d_out;

    int n_tok = in_sizes[1];
    int V0 = in_sizes[5];
    int V1 = in_sizes[6];
    int V2 = in_sizes[7];
    int N  = V0 + V1 + V2;
    int c1 = V0, c2 = V0 + V1;
    int nv0 = (V0 + 63) >> 6, nv1 = (V1 + 63) >> 6, nv2 = (V2 + 63) >> 6;
    int maxV = V0 > V1 ? V0 : V1; if (V2 > maxV) maxV = V2;
    int lstride = ((maxV + 63) >> 6) << 6;    // pad to vocab-tile multiple

    int maxGroups = (((n_tok + 255) >> 8) + 3) << 4;

    // workspace layout (256B-aligned sections)
    char* ws = (char*)d_ws;
    size_t off = 0;
    int* cnt = (int*)(ws + off);      off += 256;
    int* lists = (int*)(ws + off);    off += (((size_t)3 * n_tok * 4 + 255) & ~(size_t)255);
    unsigned short* packA = (unsigned short*)(ws + off);
    off += (((size_t)maxGroups * 8192 + 255) & ~(size_t)255);
    unsigned short* lws = (unsigned short*)(ws + off);

    classify_kernel<<<1, 1024, 0, stream>>>(targets, cnt, lists, n_tok, c1, c2);

    pack_a_kernel<<<maxGroups, 512, 0, stream>>>(x, lists, cnt, packA, n_tok);

    gemm_ws_kernel<<<nv0 + nv1 + nv2, 256, 0, stream>>>(
        packA, w0, w1, w2, b0, b1, b2, lists, cnt,
        V0, V1, V2, nv0, nv1, lws, lstride, n_tok);

    finalize_kernel<<<n_tok, 256, 0, stream>>>(
        out, lws, lstride, targets, c1, c2, N);
}

// Round 13
// 152.669 us; speedup vs baseline: 1.1193x; 1.1193x over previous
//
#include <hip/hip_runtime.h>
#include <hip/hip_bf16.h>
#include <math.h>

// ---------------------------------------------------------------------------
// MaskAdaptiveLogSoftmax, round 13 (= R9 champion + k-loop prefetch):
//   classify: bucket tokens by target cluster (1 block, deterministic)
//   pack_a:   x rows -> bf16 A-fragments in MFMA-native order (coalesced)
//   gemm:     W-stationary 64-voc tiles, 256 thr / 4 waves, wave=64tok x 64voc
//             acc[4][4]; W tile in LDS in FRAGMENT order (conflict-free
//             ds_read_b128). NEW vs R9: __launch_bounds__(256,3) for VGPR
//             headroom + explicit a_cur/a_nxt prefetch so next k-step's
//             global A-loads overlap current MFMAs.
//   finalize: one block per token row: phase1 sumexp -> lse; phase2 write
//             full row (nontemporal), active segment re-read L2-hot.
// ---------------------------------------------------------------------------

typedef __attribute__((ext_vector_type(4))) float f32x4;
typedef __attribute__((ext_vector_type(8))) short bf16x8;
typedef __attribute__((ext_vector_type(4))) unsigned short u16x4;
typedef __attribute__((ext_vector_type(8))) unsigned short u16x8;

__device__ __forceinline__ unsigned int f2bf(float f) {
    union { float f; unsigned int u; } cv; cv.f = f;
    unsigned int u = cv.u + 0x7fffu + ((cv.u >> 16) & 1u);  // RNE
    return u >> 16;
}
__device__ __forceinline__ float bf2f(unsigned short h) {
    union { unsigned int u; float f; } cv; cv.u = ((unsigned int)h) << 16;
    return cv.f;
}

__global__ __launch_bounds__(1024) void classify_kernel(
    const int* __restrict__ targets, int* cnt, int* lists,
    int n_tok, int c1, int c2) {
    __shared__ int lcnt[3];
    int tid = threadIdx.x;
    if (tid < 3) lcnt[tid] = 0;
    __syncthreads();
    for (int t = tid; t < n_tok; t += 1024) {
        int tgt = targets[t];
        int c = (tgt < c1) ? 0 : ((tgt < c2) ? 1 : 2);
        int pos = atomicAdd(&lcnt[c], 1);
        lists[c * n_tok + pos] = t;
    }
    __syncthreads();
    if (tid < 3) cnt[tid] = lcnt[tid];
}

// ---- pack A-fragments: group = 16 tokens; cell (k0, lane) = 16B ----
// packA[((base+g)*8 + k0)*512 + lane*8] (ushort units); l15=token, lg=k-eighth
__global__ __launch_bounds__(512) void pack_a_kernel(
    const float* __restrict__ x, const int* __restrict__ lists,
    const int* __restrict__ cnt, unsigned short* __restrict__ packA,
    int n_tok) {
    int it0 = (cnt[0] + 255) >> 8, it1 = (cnt[1] + 255) >> 8,
        it2 = (cnt[2] + 255) >> 8;
    int g0 = it0 * 16, g1 = it1 * 16, g2 = it2 * 16;
    int gb = blockIdx.x;
    int c, g, n, base;
    if (gb < g0)                { c = 0; g = gb;            n = cnt[0]; base = 0; }
    else if (gb < g0 + g1)      { c = 1; g = gb - g0;       n = cnt[1]; base = g0; }
    else if (gb < g0 + g1 + g2) { c = 2; g = gb - g0 - g1;  n = cnt[2]; base = g0 + g1; }
    else return;

    int tid = threadIdx.x;
    int k0 = tid >> 6, lane = tid & 63;
    int l15 = lane & 15, lg = lane >> 4;
    int pos = g * 16 + l15;
    int tok = (pos < n) ? lists[c * n_tok + pos] : -1;
    uint4 pk = make_uint4(0u, 0u, 0u, 0u);
    if (tok >= 0) {
        const float* src = x + (size_t)tok * 256 + k0 * 32 + lg * 8;
        float4 lo = *(const float4*)src;
        float4 hi = *(const float4*)(src + 4);
        pk.x = f2bf(lo.x) | (f2bf(lo.y) << 16);
        pk.y = f2bf(lo.z) | (f2bf(lo.w) << 16);
        pk.z = f2bf(hi.x) | (f2bf(hi.y) << 16);
        pk.w = f2bf(hi.z) | (f2bf(hi.w) << 16);
    }
    *(uint4*)(packA + ((size_t)(base + g) * 8 + k0) * 512 + lane * 8) = pk;
}

// ---- W-stationary GEMM: 64-voc tiles, 256 threads = 4 waves ----
// LDS holds W tile in FRAGMENT order: block (nn,k0) of 1KB; lane*16 within.
__global__ __launch_bounds__(256, 3) void gemm_ws_kernel(
    const unsigned short* __restrict__ packA,
    const float* __restrict__ w0, const float* __restrict__ w1,
    const float* __restrict__ w2,
    const float* __restrict__ b0, const float* __restrict__ b1,
    const float* __restrict__ b2,
    const int* __restrict__ lists, const int* __restrict__ cnt,
    int V0, int V1, int V2, int nv0, int nv1,
    unsigned short* __restrict__ lws, int lstride, int n_tok) {

    __shared__ __align__(16) unsigned char wlds[64 * 512];   // 32 KB
    __shared__ int tok_lds[2048];                            // 8 KB

    int bid = blockIdx.x;
    int c, vt;
    if (bid < nv0)            { c = 0; vt = bid; }
    else if (bid < nv0 + nv1) { c = 1; vt = bid - nv0; }
    else                      { c = 2; vt = bid - nv0 - nv1; }

    const float* Wc; const float* Bc; int Vc;
    if (c == 0)      { Wc = w0; Bc = b0; Vc = V0; }
    else if (c == 1) { Wc = w1; Bc = b1; Vc = V1; }
    else             { Wc = w2; Bc = b2; Vc = V2; }

    int it0 = (cnt[0] + 255) >> 8, it1 = (cnt[1] + 255) >> 8;
    int baseg = (c == 0) ? 0 : ((c == 1) ? it0 * 16 : (it0 + it1) * 16);

    int n = cnt[c];
    int nIter = (n + 255) >> 8;
    int v0 = vt * 64;
    int tid = threadIdx.x;

    // ---- stage W tile (64 rows x 256 k) fp32 -> bf16 LDS in frag order ----
    #pragma unroll
    for (int u0 = 0; u0 < 2; ++u0) {
        int u = u0 * 256 + tid;
        int row = u >> 3, seg = u & 7;
        int v = v0 + row;
        float4 f[8];
        if (v < Vc) {
            const float* src = Wc + (size_t)v * 256 + seg * 32;
            #pragma unroll
            for (int j = 0; j < 8; ++j) f[j] = *(const float4*)(src + j * 4);
        } else {
            #pragma unroll
            for (int j = 0; j < 8; ++j) f[j] = make_float4(0.f, 0.f, 0.f, 0.f);
        }
        unsigned fb = (unsigned)(((row >> 4) * 8 + seg) * 1024);
        int l15r = row & 15;
        #pragma unroll
        for (int j = 0; j < 4; ++j) {
            uint4 pk;
            pk.x = f2bf(f[2*j].x)   | (f2bf(f[2*j].y)   << 16);
            pk.y = f2bf(f[2*j].z)   | (f2bf(f[2*j].w)   << 16);
            pk.z = f2bf(f[2*j+1].x) | (f2bf(f[2*j+1].y) << 16);
            pk.w = f2bf(f[2*j+1].z) | (f2bf(f[2*j+1].w) << 16);
            *(uint4*)(wlds + fb + (j * 16 + l15r) * 16) = pk;
        }
    }
    for (int i = tid; i < nIter * 256; i += 256)
        tok_lds[i] = (i < n) ? lists[c * n_tok + i] : -1;
    __syncthreads();
    // no barriers after this point: LDS read-only

    int lane = tid & 63;
    int wid  = tid >> 6;
    int lg = lane >> 4, l15 = lane & 15;
    const char* pA = (const char*)packA;

    // -inf sentinel for vocab pad: finalize sums exp() over padded width,
    // exp(-inf)=0 keeps it exact.
    float bv[4];
    #pragma unroll
    for (int nn = 0; nn < 4; ++nn) {
        int vl = v0 + nn * 16 + l15;
        bv[nn] = (vl < Vc) ? Bc[vl] : -__builtin_huge_valf();
    }

    for (int it = 0; it < nIter; ++it) {
        int tb = it * 256 + wid * 64;
        if (tb >= n) continue;   // wave-uniform, no barriers -> safe
        const char* ga = pA + (size_t)(baseg + it * 16 + wid * 4) * 8192 + lane * 16;

        f32x4 acc[4][4];
        #pragma unroll
        for (int m = 0; m < 4; ++m)
            #pragma unroll
            for (int nn = 0; nn < 4; ++nn)
                acc[m][nn] = (f32x4){0.f, 0.f, 0.f, 0.f};

        // ---- k-loop with explicit A prefetch (a_nxt loads overlap MFMAs) --
        bf16x8 a_cur[4];
        #pragma unroll
        for (int m = 0; m < 4; ++m)
            a_cur[m] = *(const bf16x8*)(ga + m * 8192);

        #pragma unroll
        for (int k0 = 0; k0 < 8; ++k0) {
            bf16x8 a_nxt[4];
            if (k0 < 7) {
                #pragma unroll
                for (int m = 0; m < 4; ++m)
                    a_nxt[m] = *(const bf16x8*)(ga + m * 8192 + (k0 + 1) * 1024);
            }
            bf16x8 b[4];
            #pragma unroll
            for (int nn = 0; nn < 4; ++nn)
                b[nn] = *(const bf16x8*)(wlds + (nn * 8 + k0) * 1024 + lane * 16);
            #pragma unroll
            for (int m = 0; m < 4; ++m)
                #pragma unroll
                for (int nn = 0; nn < 4; ++nn)
                    acc[m][nn] = __builtin_amdgcn_mfma_f32_16x16x32_bf16(
                        a_cur[m], b[nn], acc[m][nn], 0, 0, 0);
            if (k0 < 7) {
                #pragma unroll
                for (int m = 0; m < 4; ++m) a_cur[m] = a_nxt[m];
            }
        }

        // ---- epilogue: bf16 logit stores only ----
        #pragma unroll
        for (int m = 0; m < 4; ++m) {
            #pragma unroll
            for (int rr = 0; rr < 4; ++rr) {
                int tokid = tok_lds[tb + m * 16 + lg * 4 + rr];
                if (tokid >= 0) {
                    unsigned short* dst =
                        lws + (size_t)tokid * lstride + v0 + l15;
                    #pragma unroll
                    for (int nn = 0; nn < 4; ++nn)
                        dst[nn * 16] =
                            (unsigned short)f2bf(acc[m][nn][rr] + bv[nn]);
                }
            }
        }
    }
}

// ---- fused sumexp + finalize: one block per token row ----
__global__ __launch_bounds__(256) void finalize_kernel(
    float* __restrict__ out, const unsigned short* __restrict__ lws,
    int lstride, const int* __restrict__ targets, int c1, int c2, int N) {
    __shared__ float sred[4];
    __shared__ float sL;

    int t = blockIdx.x;
    int tid = threadIdx.x;
    int tgt = targets[t];
    int l, r, V;
    if (tgt < c1)      { l = 0;  r = c1; V = c1; }
    else if (tgt < c2) { l = c1; r = c2; V = c2 - c1; }
    else               { l = c2; r = N;  V = N - c2; }

    const unsigned short* lrow = lws + (size_t)t * lstride;
    int Vp8 = (V + 7) & ~7;            // pad logits are -inf -> exp()=0

    // phase 1: read active row, sumexp
    float s = 0.f;
    for (int i = tid * 8; i < Vp8; i += 2048) {
        u16x8 u = *(const u16x8*)(lrow + i);
        s += __expf(bf2f(u.s0)) + __expf(bf2f(u.s1))
           + __expf(bf2f(u.s2)) + __expf(bf2f(u.s3))
           + __expf(bf2f(u.s4)) + __expf(bf2f(u.s5))
           + __expf(bf2f(u.s6)) + __expf(bf2f(u.s7));
    }
    s += __shfl_down(s, 32); s += __shfl_down(s, 16); s += __shfl_down(s, 8);
    s += __shfl_down(s, 4);  s += __shfl_down(s, 2);  s += __shfl_down(s, 1);
    if ((tid & 63) == 0) sred[tid >> 6] = s;
    __syncthreads();
    if (tid == 0)
        sL = logf(sred[0] + sred[1] + sred[2] + sred[3] + (float)(N - V));
    __syncthreads();
    float L = sL;

    // phase 2: write full row (nt); active segment re-read is L2-hot
    float* orow = out + (size_t)t * N;
    f32x4 neg = (f32x4){-L, -L, -L, -L};
    for (int i4 = tid * 4; i4 < N; i4 += 1024) {
        f32x4 res;
        if (i4 >= l && i4 < r) {      // cluster bounds are multiples of 4
            u16x4 u = *(const u16x4*)(lrow + (i4 - l));
            res = (f32x4){bf2f(u.x) - L, bf2f(u.y) - L,
                          bf2f(u.z) - L, bf2f(u.w) - L};
        } else {
            res = neg;
        }
        __builtin_nontemporal_store(res, (f32x4*)(orow + i4));
    }
}

extern "C" void kernel_launch(void* const* d_in, const int* in_sizes, int n_in,
                              void* d_out, int out_size, void* d_ws, size_t ws_size,
                              hipStream_t stream) {
    const float* x       = (const float*)d_in[0];
    const int*   targets = (const int*)d_in[1];
    const float* w0      = (const float*)d_in[2];
    const float* w1      = (const float*)d_in[3];
    const float* w2      = (const float*)d_in[4];
    const float* b0      = (const float*)d_in[5];
    const float* b1      = (const float*)d_in[6];
    const float* b2      = (const float*)d_in[7];
    float* out = (float*)d_out;

    int n_tok = in_sizes[1];
    int V0 = in_sizes[5];
    int V1 = in_sizes[6];
    int V2 = in_sizes[7];
    int N  = V0 + V1 + V2;
    int c1 = V0, c2 = V0 + V1;
    int nv0 = (V0 + 63) >> 6, nv1 = (V1 + 63) >> 6, nv2 = (V2 + 63) >> 6;
    int maxV = V0 > V1 ? V0 : V1; if (V2 > maxV) maxV = V2;
    int lstride = ((maxV + 63) >> 6) << 6;    // pad to vocab-tile multiple

    // worst-case packed A groups: sum_c ceil(cnt_c/256)*16 <= (ceil(n/256)+3)*16
    int maxGroups = (((n_tok + 255) >> 8) + 3) << 4;

    // workspace layout (256B-aligned sections)
    char* ws = (char*)d_ws;
    size_t off = 0;
    int* cnt = (int*)(ws + off);      off += 256;
    int* lists = (int*)(ws + off);    off += (((size_t)3 * n_tok * 4 + 255) & ~(size_t)255);
    unsigned short* packA = (unsigned short*)(ws + off);
    off += (((size_t)maxGroups * 8192 + 255) & ~(size_t)255);
    unsigned short* lws = (unsigned short*)(ws + off);

    classify_kernel<<<1, 1024, 0, stream>>>(targets, cnt, lists, n_tok, c1, c2);

    pack_a_kernel<<<maxGroups, 512, 0, stream>>>(x, lists, cnt, packA, n_tok);

    gemm_ws_kernel<<<nv0 + nv1 + nv2, 256, 0, stream>>>(
        packA, w0, w1, w2, b0, b1, b2, lists, cnt,
        V0, V1, V2, nv0, nv1, lws, lstride, n_tok);

    finalize_kernel<<<n_tok, 256, 0, stream>>>(
        out, lws, lstride, targets, c1, c2, N);
}

// Round 14
// 150.891 us; speedup vs baseline: 1.1325x; 1.0118x over previous
//
#include <hip/hip_runtime.h>
#include <hip/hip_bf16.h>
#include <math.h>

// ---------------------------------------------------------------------------
// MaskAdaptiveLogSoftmax, round 14 (= R9 champion, GEMM at 8 waves/block):
//   classify: bucket tokens by target cluster (1 block, deterministic)
//   pack_a:   x rows -> bf16 A-fragments in MFMA-native order (coalesced)
//   gemm:     W-stationary 64-voc tiles, 512 thr / 8 waves (16 waves/CU for
//             TLP), wave = 64tok x 64voc, acc[4][4]; W tile in LDS in
//             FRAGMENT order (conflict-free ds_read_b128). Wave-pairs split
//             token iters (0-3 even, 4-7 odd). Epilogue: bf16 logit stores.
//   finalize: one block per token row: phase1 sumexp -> lse; phase2 write
//             full row (nontemporal), active segment re-read L2-hot.
// ---------------------------------------------------------------------------

typedef __attribute__((ext_vector_type(4))) float f32x4;
typedef __attribute__((ext_vector_type(8))) short bf16x8;
typedef __attribute__((ext_vector_type(4))) unsigned short u16x4;
typedef __attribute__((ext_vector_type(8))) unsigned short u16x8;

__device__ __forceinline__ unsigned int f2bf(float f) {
    union { float f; unsigned int u; } cv; cv.f = f;
    unsigned int u = cv.u + 0x7fffu + ((cv.u >> 16) & 1u);  // RNE
    return u >> 16;
}
__device__ __forceinline__ float bf2f(unsigned short h) {
    union { unsigned int u; float f; } cv; cv.u = ((unsigned int)h) << 16;
    return cv.f;
}

__global__ __launch_bounds__(1024) void classify_kernel(
    const int* __restrict__ targets, int* cnt, int* lists,
    int n_tok, int c1, int c2) {
    __shared__ int lcnt[3];
    int tid = threadIdx.x;
    if (tid < 3) lcnt[tid] = 0;
    __syncthreads();
    for (int t = tid; t < n_tok; t += 1024) {
        int tgt = targets[t];
        int c = (tgt < c1) ? 0 : ((tgt < c2) ? 1 : 2);
        int pos = atomicAdd(&lcnt[c], 1);
        lists[c * n_tok + pos] = t;
    }
    __syncthreads();
    if (tid < 3) cnt[tid] = lcnt[tid];
}

// ---- pack A-fragments: group = 16 tokens; cell (k0, lane) = 16B ----
// packA[((base+g)*8 + k0)*512 + lane*8] (ushort units); l15=token, lg=k-eighth
__global__ __launch_bounds__(512) void pack_a_kernel(
    const float* __restrict__ x, const int* __restrict__ lists,
    const int* __restrict__ cnt, unsigned short* __restrict__ packA,
    int n_tok) {
    int it0 = (cnt[0] + 255) >> 8, it1 = (cnt[1] + 255) >> 8,
        it2 = (cnt[2] + 255) >> 8;
    int g0 = it0 * 16, g1 = it1 * 16, g2 = it2 * 16;
    int gb = blockIdx.x;
    int c, g, n, base;
    if (gb < g0)                { c = 0; g = gb;            n = cnt[0]; base = 0; }
    else if (gb < g0 + g1)      { c = 1; g = gb - g0;       n = cnt[1]; base = g0; }
    else if (gb < g0 + g1 + g2) { c = 2; g = gb - g0 - g1;  n = cnt[2]; base = g0 + g1; }
    else return;

    int tid = threadIdx.x;
    int k0 = tid >> 6, lane = tid & 63;
    int l15 = lane & 15, lg = lane >> 4;
    int pos = g * 16 + l15;
    int tok = (pos < n) ? lists[c * n_tok + pos] : -1;
    uint4 pk = make_uint4(0u, 0u, 0u, 0u);
    if (tok >= 0) {
        const float* src = x + (size_t)tok * 256 + k0 * 32 + lg * 8;
        float4 lo = *(const float4*)src;
        float4 hi = *(const float4*)(src + 4);
        pk.x = f2bf(lo.x) | (f2bf(lo.y) << 16);
        pk.y = f2bf(lo.z) | (f2bf(lo.w) << 16);
        pk.z = f2bf(hi.x) | (f2bf(hi.y) << 16);
        pk.w = f2bf(hi.z) | (f2bf(hi.w) << 16);
    }
    *(uint4*)(packA + ((size_t)(base + g) * 8 + k0) * 512 + lane * 8) = pk;
}

// ---- W-stationary GEMM: 64-voc tiles, 512 threads = 8 waves ----
// LDS holds W tile in FRAGMENT order: block (nn,k0) of 1KB; lane*16 within.
// Wave-pairs split token iterations: waves 0-3 even iters, 4-7 odd iters.
__global__ __launch_bounds__(512, 2) void gemm_ws_kernel(
    const unsigned short* __restrict__ packA,
    const float* __restrict__ w0, const float* __restrict__ w1,
    const float* __restrict__ w2,
    const float* __restrict__ b0, const float* __restrict__ b1,
    const float* __restrict__ b2,
    const int* __restrict__ lists, const int* __restrict__ cnt,
    int V0, int V1, int V2, int nv0, int nv1,
    unsigned short* __restrict__ lws, int lstride, int n_tok) {

    __shared__ __align__(16) unsigned char wlds[64 * 512];   // 32 KB
    __shared__ int tok_lds[2048];                            // 8 KB

    int bid = blockIdx.x;
    int c, vt;
    if (bid < nv0)            { c = 0; vt = bid; }
    else if (bid < nv0 + nv1) { c = 1; vt = bid - nv0; }
    else                      { c = 2; vt = bid - nv0 - nv1; }

    const float* Wc; const float* Bc; int Vc;
    if (c == 0)      { Wc = w0; Bc = b0; Vc = V0; }
    else if (c == 1) { Wc = w1; Bc = b1; Vc = V1; }
    else             { Wc = w2; Bc = b2; Vc = V2; }

    int it0 = (cnt[0] + 255) >> 8, it1 = (cnt[1] + 255) >> 8;
    int baseg = (c == 0) ? 0 : ((c == 1) ? it0 * 16 : (it0 + it1) * 16);

    int n = cnt[c];
    int nIter = (n + 255) >> 8;
    int v0 = vt * 64;
    int tid = threadIdx.x;

    // ---- stage W tile (64 rows x 256 k) fp32 -> bf16 LDS in frag order ----
    {
        int u = tid;                  // 512 units of 64B
        int row = u >> 3, seg = u & 7;
        int v = v0 + row;
        float4 f[8];
        if (v < Vc) {
            const float* src = Wc + (size_t)v * 256 + seg * 32;
            #pragma unroll
            for (int j = 0; j < 8; ++j) f[j] = *(const float4*)(src + j * 4);
        } else {
            #pragma unroll
            for (int j = 0; j < 8; ++j) f[j] = make_float4(0.f, 0.f, 0.f, 0.f);
        }
        unsigned fb = (unsigned)(((row >> 4) * 8 + seg) * 1024);
        int l15r = row & 15;
        #pragma unroll
        for (int j = 0; j < 4; ++j) {
            uint4 pk;
            pk.x = f2bf(f[2*j].x)   | (f2bf(f[2*j].y)   << 16);
            pk.y = f2bf(f[2*j].z)   | (f2bf(f[2*j].w)   << 16);
            pk.z = f2bf(f[2*j+1].x) | (f2bf(f[2*j+1].y) << 16);
            pk.w = f2bf(f[2*j+1].z) | (f2bf(f[2*j+1].w) << 16);
            *(uint4*)(wlds + fb + (j * 16 + l15r) * 16) = pk;
        }
    }
    for (int i = tid; i < nIter * 256; i += 512)
        tok_lds[i] = (i < n) ? lists[c * n_tok + i] : -1;
    __syncthreads();
    // no barriers after this point: LDS read-only

    int lane = tid & 63;
    int wid  = tid >> 6;          // 0..7
    int wpair = wid >> 2;         // 0/1: even/odd iteration split
    int wq    = wid & 3;          // token quarter within iteration
    int lg = lane >> 4, l15 = lane & 15;
    const char* pA = (const char*)packA;

    // -inf sentinel for vocab pad: finalize sums exp() over padded width,
    // exp(-inf)=0 keeps it exact.
    float bv[4];
    #pragma unroll
    for (int nn = 0; nn < 4; ++nn) {
        int vl = v0 + nn * 16 + l15;
        bv[nn] = (vl < Vc) ? Bc[vl] : -__builtin_huge_valf();
    }

    for (int it = wpair; it < nIter; it += 2) {
        int tb = it * 256 + wq * 64;
        if (tb >= n) continue;   // wave-uniform, no barriers -> safe
        const char* ga = pA + (size_t)(baseg + it * 16 + wq * 4) * 8192 + lane * 16;

        f32x4 acc[4][4];
        #pragma unroll
        for (int m = 0; m < 4; ++m)
            #pragma unroll
            for (int nn = 0; nn < 4; ++nn)
                acc[m][nn] = (f32x4){0.f, 0.f, 0.f, 0.f};

        #pragma unroll
        for (int k0 = 0; k0 < 8; ++k0) {
            bf16x8 a[4], b[4];
            #pragma unroll
            for (int m = 0; m < 4; ++m)
                a[m] = *(const bf16x8*)(ga + m * 8192 + k0 * 1024);
            #pragma unroll
            for (int nn = 0; nn < 4; ++nn)
                b[nn] = *(const bf16x8*)(wlds + (nn * 8 + k0) * 1024 + lane * 16);
            #pragma unroll
            for (int m = 0; m < 4; ++m)
                #pragma unroll
                for (int nn = 0; nn < 4; ++nn)
                    acc[m][nn] = __builtin_amdgcn_mfma_f32_16x16x32_bf16(
                        a[m], b[nn], acc[m][nn], 0, 0, 0);
        }

        // ---- epilogue: bf16 logit stores only ----
        #pragma unroll
        for (int m = 0; m < 4; ++m) {
            #pragma unroll
            for (int rr = 0; rr < 4; ++rr) {
                int tokid = tok_lds[tb + m * 16 + lg * 4 + rr];
                if (tokid >= 0) {
                    unsigned short* dst =
                        lws + (size_t)tokid * lstride + v0 + l15;
                    #pragma unroll
                    for (int nn = 0; nn < 4; ++nn)
                        dst[nn * 16] =
                            (unsigned short)f2bf(acc[m][nn][rr] + bv[nn]);
                }
            }
        }
    }
}

// ---- fused sumexp + finalize: one block per token row ----
__global__ __launch_bounds__(256) void finalize_kernel(
    float* __restrict__ out, const unsigned short* __restrict__ lws,
    int lstride, const int* __restrict__ targets, int c1, int c2, int N) {
    __shared__ float sred[4];
    __shared__ float sL;

    int t = blockIdx.x;
    int tid = threadIdx.x;
    int tgt = targets[t];
    int l, r, V;
    if (tgt < c1)      { l = 0;  r = c1; V = c1; }
    else if (tgt < c2) { l = c1; r = c2; V = c2 - c1; }
    else               { l = c2; r = N;  V = N - c2; }

    const unsigned short* lrow = lws + (size_t)t * lstride;
    int Vp8 = (V + 7) & ~7;            // pad logits are -inf -> exp()=0

    // phase 1: read active row, sumexp
    float s = 0.f;
    for (int i = tid * 8; i < Vp8; i += 2048) {
        u16x8 u = *(const u16x8*)(lrow + i);
        s += __expf(bf2f(u.s0)) + __expf(bf2f(u.s1))
           + __expf(bf2f(u.s2)) + __expf(bf2f(u.s3))
           + __expf(bf2f(u.s4)) + __expf(bf2f(u.s5))
           + __expf(bf2f(u.s6)) + __expf(bf2f(u.s7));
    }
    s += __shfl_down(s, 32); s += __shfl_down(s, 16); s += __shfl_down(s, 8);
    s += __shfl_down(s, 4);  s += __shfl_down(s, 2);  s += __shfl_down(s, 1);
    if ((tid & 63) == 0) sred[tid >> 6] = s;
    __syncthreads();
    if (tid == 0)
        sL = logf(sred[0] + sred[1] + sred[2] + sred[3] + (float)(N - V));
    __syncthreads();
    float L = sL;

    // phase 2: write full row (nt); active segment re-read is L2-hot
    float* orow = out + (size_t)t * N;
    f32x4 neg = (f32x4){-L, -L, -L, -L};
    for (int i4 = tid * 4; i4 < N; i4 += 1024) {
        f32x4 res;
        if (i4 >= l && i4 < r) {      // cluster bounds are multiples of 4
            u16x4 u = *(const u16x4*)(lrow + (i4 - l));
            res = (f32x4){bf2f(u.x) - L, bf2f(u.y) - L,
                          bf2f(u.z) - L, bf2f(u.w) - L};
        } else {
            res = neg;
        }
        __builtin_nontemporal_store(res, (f32x4*)(orow + i4));
    }
}

extern "C" void kernel_launch(void* const* d_in, const int* in_sizes, int n_in,
                              void* d_out, int out_size, void* d_ws, size_t ws_size,
                              hipStream_t stream) {
    const float* x       = (const float*)d_in[0];
    const int*   targets = (const int*)d_in[1];
    const float* w0      = (const float*)d_in[2];
    const float* w1      = (const float*)d_in[3];
    const float* w2      = (const float*)d_in[4];
    const float* b0      = (const float*)d_in[5];
    const float* b1      = (const float*)d_in[6];
    const float* b2      = (const float*)d_in[7];
    float* out = (float*)d_out;

    int n_tok = in_sizes[1];
    int V0 = in_sizes[5];
    int V1 = in_sizes[6];
    int V2 = in_sizes[7];
    int N  = V0 + V1 + V2;
    int c1 = V0, c2 = V0 + V1;
    int nv0 = (V0 + 63) >> 6, nv1 = (V1 + 63) >> 6, nv2 = (V2 + 63) >> 6;
    int maxV = V0 > V1 ? V0 : V1; if (V2 > maxV) maxV = V2;
    int lstride = ((maxV + 63) >> 6) << 6;    // pad to vocab-tile multiple

    // worst-case packed A groups: sum_c ceil(cnt_c/256)*16 <= (ceil(n/256)+3)*16
    int maxGroups = (((n_tok + 255) >> 8) + 3) << 4;

    // workspace layout (256B-aligned sections)
    char* ws = (char*)d_ws;
    size_t off = 0;
    int* cnt = (int*)(ws + off);      off += 256;
    int* lists = (int*)(ws + off);    off += (((size_t)3 * n_tok * 4 + 255) & ~(size_t)255);
    unsigned short* packA = (unsigned short*)(ws + off);
    off += (((size_t)maxGroups * 8192 + 255) & ~(size_t)255);
    unsigned short* lws = (unsigned short*)(ws + off);

    classify_kernel<<<1, 1024, 0, stream>>>(targets, cnt, lists, n_tok, c1, c2);

    pack_a_kernel<<<maxGroups, 512, 0, stream>>>(x, lists, cnt, packA, n_tok);

    gemm_ws_kernel<<<nv0 + nv1 + nv2, 512, 0, stream>>>(
        packA, w0, w1, w2, b0, b1, b2, lists, cnt,
        V0, V1, V2, nv0, nv1, lws, lstride, n_tok);

    finalize_kernel<<<n_tok, 256, 0, stream>>>(
        out, lws, lstride, targets, c1, c2, N);
}